// Round 5
// baseline (139.115 us; speedup 1.0000x reference)
//
#include <hip/hip_runtime.h>
#include <math.h>

#define BT 32768   // B*T tokens
#define DD 1024    // feature dim
#define NN 512     // buffer slots
#define PP 1024    // partial-sum blocks

typedef float v4f __attribute__((ext_vector_type(4)));

__device__ __forceinline__ float fast_gelu(float x) {
    // 0.5*x*(1+tanh(c*(x+0.044715 x^3))), tanh(u) = 1 - 2/(exp(2u)+1)
    float u = 0.7978845608028654f * (x + 0.044715f * x * x * x);
    float e = __expf(2.0f * u);
    float t = 1.0f - __fdividef(2.0f, e + 1.0f);
    return 0.5f * x * (1.0f + t);
}

// Kernel 1: per-column partial sums of gelu(x). Strided rows (Round-3-proven):
// at any instant the 1024 blocks sweep one contiguous 4 MB slab of x.
// Block 0 zeroes the finisher counters for kernels 2/3 (kernel-boundary visibility).
__global__ __launch_bounds__(256) void k_partial(const v4f* __restrict__ x4,
                                                 v4f* __restrict__ part,
                                                 int* __restrict__ cnts) {
    if (blockIdx.x == 0 && threadIdx.x == 0) { cnts[0] = 0; cnts[1] = 0; }
    int t = threadIdx.x;
    v4f acc = {0.f, 0.f, 0.f, 0.f};
    for (int row = blockIdx.x; row < BT; row += PP) {
        v4f v = x4[row * (DD / 4) + t];
        acc.x += fast_gelu(v.x);
        acc.y += fast_gelu(v.y);
        acc.z += fast_gelu(v.z);
        acc.w += fast_gelu(v.w);
    }
    part[blockIdx.x * (DD / 4) + t] = acc;
}

// Kernel 2: 64 blocks reduce part[1024][1024] -> part2[64][1024]; last block to
// finish computes mean, norm, m_n.
__global__ __launch_bounds__(256) void k_reduce_mean(const float* __restrict__ part,
                                                     float* __restrict__ part2,
                                                     float* __restrict__ m_mean,
                                                     float* __restrict__ m_n,
                                                     float* __restrict__ nm_out,
                                                     int* __restrict__ cnts) {
    int t = threadIdx.x, j = blockIdx.x;
    float a0 = 0, a1 = 0, a2 = 0, a3 = 0;
    for (int r = 0; r < 16; ++r) {
        const float* row = part + (j * 16 + r) * DD;
        a0 += row[t];
        a1 += row[t + 256];
        a2 += row[t + 512];
        a3 += row[t + 768];
    }
    part2[j * DD + t] = a0;
    part2[j * DD + t + 256] = a1;
    part2[j * DD + t + 512] = a2;
    part2[j * DD + t + 768] = a3;
    __threadfence();
    __shared__ int sLast;
    if (t == 0) {
        int old = __hip_atomic_fetch_add(&cnts[0], 1, __ATOMIC_ACQ_REL, __HIP_MEMORY_SCOPE_AGENT);
        sLast = (old == 63) ? 1 : 0;
    }
    __syncthreads();
    if (!sLast) return;
    __threadfence();
    float s0 = 0, s1 = 0, s2 = 0, s3 = 0;
    for (int jj = 0; jj < 64; ++jj) {
        const float* row = part2 + jj * DD;
        s0 += row[t];
        s1 += row[t + 256];
        s2 += row[t + 512];
        s3 += row[t + 768];
    }
    const float inv = 1.0f / 32768.0f;
    float m0 = s0 * inv, m1 = s1 * inv, m2 = s2 * inv, m3 = s3 * inv;
    m_mean[t] = m0;
    m_mean[t + 256] = m1;
    m_mean[t + 512] = m2;
    m_mean[t + 768] = m3;
    __shared__ float red[256];
    red[t] = m0 * m0 + m1 * m1 + m2 * m2 + m3 * m3;
    __syncthreads();
    for (int st = 128; st > 0; st >>= 1) {
        if (t < st) red[t] += red[t + st];
        __syncthreads();
    }
    float nm = sqrtf(red[0]);
    float den = fmaxf(nm, 1e-12f);
    m_n[t] = m0 / den;
    m_n[t + 256] = m1 / den;
    m_n[t + 512] = m2 / den;
    m_n[t + 768] = m3 / den;
    if (t == 0) nm_out[0] = nm;
}

// Kernel 3: 512 blocks compute dot[n], sq[n]; last block does argmax
// (first-index tie-break), gate, and small state outputs.
__global__ __launch_bounds__(256) void k_sims_state(const v4f* __restrict__ buf4,
                                                    const float* __restrict__ m_meanf,
                                                    const float* __restrict__ nm_p,
                                                    const float* __restrict__ depl,
                                                    const int* __restrict__ hits,
                                                    const int* __restrict__ mask,
                                                    const float* __restrict__ logk,
                                                    const float* __restrict__ loglam,
                                                    const int* __restrict__ ptrp,
                                                    float* __restrict__ dot,
                                                    float* __restrict__ sq,
                                                    float* __restrict__ out_depl,
                                                    float* __restrict__ out_hits,
                                                    float* __restrict__ out_mask,
                                                    float* __restrict__ gate_p,
                                                    int* __restrict__ cnts) {
    int t = threadIdx.x, n = blockIdx.x;
    const v4f* m4 = (const v4f*)m_meanf;
    v4f b = buf4[n * (DD / 4) + t];
    v4f m = m4[t];
    float d = b.x * m.x + b.y * m.y + b.z * m.z + b.w * m.w;
    float q = b.x * b.x + b.y * b.y + b.z * b.z + b.w * b.w;
    __shared__ float rd[256], rq[256];
    rd[t] = d;
    rq[t] = q;
    __syncthreads();
    for (int st = 128; st > 0; st >>= 1) {
        if (t < st) { rd[t] += rd[t + st]; rq[t] += rq[t + st]; }
        __syncthreads();
    }
    if (t == 0) { dot[n] = rd[0]; sq[n] = rq[0]; }
    __threadfence();
    __shared__ int sLast;
    if (t == 0) {
        int old = __hip_atomic_fetch_add(&cnts[1], 1, __ATOMIC_ACQ_REL, __HIP_MEMORY_SCOPE_AGENT);
        sLast = (old == NN - 1) ? 1 : 0;
    }
    __syncthreads();
    if (!sLast) return;
    __threadfence();

    // finisher: 256 threads handle rows t and t+256
    float nm = fmaxf(nm_p[0], 1e-12f);
    float sA = mask[t] ? dot[t] / (fmaxf(sqrtf(sq[t]), 1e-12f) * nm) : -1.0f;
    float sB = mask[t + 256] ? dot[t + 256] / (fmaxf(sqrtf(sq[t + 256]), 1e-12f) * nm) : -1.0f;
    float bs;
    int bi;
    if (sB > sA) { bs = sB; bi = t + 256; } else { bs = sA; bi = t; }
    __shared__ float sv[256];
    __shared__ int si[256];
    sv[t] = bs;
    si[t] = bi;
    __syncthreads();
    for (int st = 128; st > 0; st >>= 1) {
        if (t < st) {
            float o = sv[t + st];
            int oi = si[t + st];
            if (o > sv[t] || (o == sv[t] && oi < si[t])) { sv[t] = o; si[t] = oi; }
        }
        __syncthreads();
    }
    __shared__ int s_near, s_fired;
    if (t == 0) {
        int nearest = si[0];
        float msim = sv[0];
        float k_depl = fminf(fmaxf(expf(logk[0]), 0.1f), 5.0f);
        float lam = fminf(fmaxf(expf(loglam[0]), 0.1f), 3.0f);
        gate_p[0] = expf(-k_depl * (1.0f - depl[nearest]) - lam * (float)hits[nearest]);
        s_near = nearest;
        s_fired = (msim > 0.85f) ? 1 : 0;
    }
    __syncthreads();
    int ptr = ptrp[0];
    for (int k = 0; k < 2; ++k) {
        int nn = t + k * 256;
        float ndv = depl[nn];
        int nh = hits[nn];
        float nmsk = mask[nn] ? 1.0f : 0.0f;
        if (nn == s_near && s_fired) { ndv *= 0.5f; nh += 1; }
        if (nn == ptr) { ndv = 1.0f; nh = 0; nmsk = 1.0f; }
        out_depl[nn] = ndv;
        out_hits[nn] = (float)nh;
        out_mask[nn] = nmsk;
    }
}

// Kernel 4: blocks [0,2048): out = gelu(x)*gate, grid-stride, REGULAR stores
//           (NT stores measured -35us in R4 — rejected).
//           blocks [2048,2080): new_buf = buf with row ptr = m_n.
__global__ __launch_bounds__(256) void k_outbuf(const v4f* __restrict__ x4,
                                                v4f* __restrict__ o4,
                                                const v4f* __restrict__ buf4,
                                                const v4f* __restrict__ mn4,
                                                v4f* __restrict__ ob4,
                                                const float* __restrict__ gate_p,
                                                const int* __restrict__ ptrp) {
    int t = threadIdx.x;
    if (blockIdx.x < 2048) {
        float g = gate_p[0];
        for (int i = blockIdx.x * 256 + t; i < 8388608; i += 524288) {
            v4f v = x4[i];
            v4f r;
            r.x = fast_gelu(v.x) * g;
            r.y = fast_gelu(v.y) * g;
            r.z = fast_gelu(v.z) * g;
            r.w = fast_gelu(v.w) * g;
            o4[i] = r;
        }
    } else {
        int b2 = blockIdx.x - 2048;  // 0..31
        int ptr = ptrp[0];
        for (int k = 0; k < 16; ++k) {
            int i = b2 * 4096 + k * 256 + t;  // 131072 float4 total
            int row = i >> 8;
            v4f v = (row == ptr) ? mn4[i & 255] : buf4[i];
            ob4[i] = v;
        }
    }
}

extern "C" void kernel_launch(void* const* d_in, const int* in_sizes, int n_in,
                              void* d_out, int out_size, void* d_ws, size_t ws_size,
                              hipStream_t stream) {
    const float* x = (const float*)d_in[0];
    const float* log_k = (const float*)d_in[1];
    const float* log_lambda = (const float*)d_in[2];
    const float* buf = (const float*)d_in[3];
    const float* depl = (const float*)d_in[4];
    const int* hits = (const int*)d_in[5];
    const int* mask = (const int*)d_in[6];  // bool pushed as int32
    const int* ptr = (const int*)d_in[7];

    float* out = (float*)d_out;
    float* out_buf = out + 33554432;      // N*D
    float* out_depl = out_buf + NN * DD;  // 512
    float* out_hits = out_depl + NN;      // 512
    float* out_mask = out_hits + NN;      // 512

    // small scratch in ws (~13 KB)
    int* cnts = (int*)d_ws;          // [0]=kernel2 counter, [1]=kernel3 counter
    float* wsf = (float*)d_ws;
    float* m_mean = wsf + 16;        // 1024 (64 B aligned)
    float* m_n = wsf + 1040;         // 1024
    float* nm = wsf + 2064;          // 1
    float* gate = wsf + 2065;        // 1
    float* dot = wsf + 2080;         // 512
    float* sq = wsf + 2592;          // 512

    // big scratch lives in the output region, consumed before k_outbuf overwrites:
    float* part = out;                 // [1024][1024] = 4 MB
    float* part2 = out + 16777216;     // [64][1024] = 256 KB

    k_partial<<<dim3(PP), dim3(256), 0, stream>>>((const v4f*)x, (v4f*)part, cnts);
    k_reduce_mean<<<dim3(64), dim3(256), 0, stream>>>(part, part2, m_mean, m_n, nm, cnts);
    k_sims_state<<<dim3(NN), dim3(256), 0, stream>>>((const v4f*)buf, m_mean, nm, depl, hits,
                                                     mask, log_k, log_lambda, ptr,
                                                     dot, sq, out_depl, out_hits, out_mask,
                                                     gate, cnts);
    k_outbuf<<<dim3(2080), dim3(256), 0, stream>>>((const v4f*)x, (v4f*)out,
                                                   (const v4f*)buf, (const v4f*)m_n,
                                                   (v4f*)out_buf, gate, ptr);
}

// Round 7
// 101.868 us; speedup vs baseline: 1.3656x; 1.3656x over previous
//
#include <hip/hip_runtime.h>
#include <math.h>

#define BT 32768   // B*T tokens
#define DD 1024    // feature dim
#define NN 512     // buffer slots
#define PP 1024    // partial-sum blocks

typedef float v4f __attribute__((ext_vector_type(4)));

__device__ __forceinline__ float fast_gelu(float x) {
    // 0.5*x*(1+tanh(c*(x+0.044715 x^3))), tanh(u) = 1 - 2/(exp(2u)+1)
    float u = 0.7978845608028654f * (x + 0.044715f * x * x * x);
    float e = __expf(2.0f * u);
    float t = 1.0f - __fdividef(2.0f, e + 1.0f);
    return 0.5f * x * (1.0f + t);
}

// Pass 1a: per-column partial sums of gelu(x). part[PP][DD]  (R3-proven)
__global__ __launch_bounds__(256) void k_partial(const v4f* __restrict__ x4,
                                                 v4f* __restrict__ part) {
    int t = threadIdx.x;  // 0..255 -> cols 4t..4t+3
    v4f acc = {0.f, 0.f, 0.f, 0.f};
    for (int row = blockIdx.x; row < BT; row += PP) {
        v4f v = x4[row * (DD / 4) + t];
        acc.x += fast_gelu(v.x);
        acc.y += fast_gelu(v.y);
        acc.z += fast_gelu(v.z);
        acc.w += fast_gelu(v.w);
    }
    part[blockIdx.x * (DD / 4) + t] = acc;
}

// Pass 1b: reduce PP partial rows -> 16 rows. 64 blocks x 256 thr.  (R3-proven)
__global__ __launch_bounds__(256) void k_reduce1(const float* __restrict__ part,
                                                 float* __restrict__ part2) {
    int g = blockIdx.x * 256 + threadIdx.x;  // 0..16383
    int col = g & (DD - 1);
    int chunk = g >> 10;  // 0..15
    float s = 0.f;
    int r0 = chunk * (PP / 16);
    for (int r = r0; r < r0 + PP / 16; ++r) s += part[r * DD + col];
    part2[chunk * DD + col] = s;
}

// Pass 1c: final mean, norm, normalized mean. 1 block x 1024 thr.  (R3-proven)
__global__ __launch_bounds__(1024) void k_mean_norm(const float* __restrict__ part2,
                                                    float* __restrict__ m_mean,
                                                    float* __restrict__ m_n,
                                                    float* __restrict__ nm_out) {
    int c = threadIdx.x;
    float s = 0.f;
    for (int r = 0; r < 16; ++r) s += part2[r * DD + c];
    float m = s * (1.0f / 32768.0f);
    m_mean[c] = m;
    __shared__ float red[1024];
    red[c] = m * m;
    __syncthreads();
    for (int st = 512; st > 0; st >>= 1) {
        if (c < st) red[c] += red[c + st];
        __syncthreads();
    }
    float nm = sqrtf(red[0]);
    float denom = fmaxf(nm, 1e-12f);
    m_n[c] = m / denom;
    if (c == 0) nm_out[0] = nm;
}

// sims prep: dot[n] = buf[n].m_mean ; sq[n] = ||buf[n]||^2. 512 blocks x 256 thr.  (R3-proven)
__global__ __launch_bounds__(256) void k_sims(const v4f* __restrict__ buf4,
                                              const v4f* __restrict__ m4,
                                              float* __restrict__ dot,
                                              float* __restrict__ sq) {
    int n = blockIdx.x;
    int t = threadIdx.x;
    v4f b = buf4[n * (DD / 4) + t];
    v4f m = m4[t];
    float d = b.x * m.x + b.y * m.y + b.z * m.z + b.w * m.w;
    float q = b.x * b.x + b.y * b.y + b.z * b.z + b.w * b.w;
    __shared__ float rd[256], rq[256];
    rd[t] = d;
    rq[t] = q;
    __syncthreads();
    for (int st = 128; st > 0; st >>= 1) {
        if (t < st) { rd[t] += rd[t + st]; rq[t] += rq[t + st]; }
        __syncthreads();
    }
    if (t == 0) { dot[n] = rd[0]; sq[n] = rq[0]; }
}

// argmax (first-index tie-break), gate, fired, small state outputs. 1 block x 512 thr.  (R3-proven)
__global__ __launch_bounds__(512) void k_state(const float* __restrict__ dot,
                                               const float* __restrict__ sq,
                                               const float* __restrict__ nm_p,
                                               const float* __restrict__ depl,
                                               const int* __restrict__ hits,
                                               const int* __restrict__ mask,   // int32 on device
                                               const float* __restrict__ logk_p,
                                               const float* __restrict__ loglam_p,
                                               const int* __restrict__ ptr_p,
                                               float* __restrict__ out_depl,
                                               float* __restrict__ out_hits,
                                               float* __restrict__ out_mask,
                                               float* __restrict__ gate_p) {
    int n = threadIdx.x;
    float nm = fmaxf(nm_p[0], 1e-12f);
    float nb = fmaxf(sqrtf(sq[n]), 1e-12f);
    bool mk = mask[n] != 0;
    float sim = mk ? dot[n] / (nb * nm) : -1.0f;

    __shared__ float ssim[512];
    __shared__ int sidx[512];
    ssim[n] = sim;
    sidx[n] = n;
    __syncthreads();
    for (int st = 256; st > 0; st >>= 1) {
        if (n < st) {
            float s2 = ssim[n + st];
            int i2 = sidx[n + st];
            if (s2 > ssim[n] || (s2 == ssim[n] && i2 < sidx[n])) {
                ssim[n] = s2;
                sidx[n] = i2;
            }
        }
        __syncthreads();
    }

    __shared__ int s_near, s_fired;
    if (n == 0) {
        int nearest = sidx[0];
        float msim = ssim[0];
        float k_depl = fminf(fmaxf(expf(logk_p[0]), 0.1f), 5.0f);
        float lam = fminf(fmaxf(expf(loglam_p[0]), 0.1f), 3.0f);
        float g = expf(-k_depl * (1.0f - depl[nearest]) - lam * (float)hits[nearest]);
        s_near = nearest;
        s_fired = (msim > 0.85f) ? 1 : 0;
        gate_p[0] = g;
    }
    __syncthreads();

    int ptr = ptr_p[0];
    float nd = depl[n];
    int nh = hits[n];
    float nmsk = mk ? 1.0f : 0.0f;
    if (n == s_near && s_fired) { nd *= 0.5f; nh += 1; }
    if (n == ptr) { nd = 1.0f; nh = 0; nmsk = 1.0f; }
    out_depl[n] = nd;
    out_hits[n] = (float)nh;
    out_mask[n] = nmsk;
}

// Pass 2: blocks [0,2048): out = gelu(x)*gate, grid-stride, regular stores (R3-proven).
//         blocks [2048,2080): new_buf = buf with row ptr = m_n (fence-free merge).
__global__ __launch_bounds__(256) void k_outbuf(const v4f* __restrict__ x4,
                                                v4f* __restrict__ o4,
                                                const v4f* __restrict__ buf4,
                                                const v4f* __restrict__ mn4,
                                                v4f* __restrict__ ob4,
                                                const float* __restrict__ gate_p,
                                                const int* __restrict__ ptrp) {
    int t = threadIdx.x;
    if (blockIdx.x < 2048) {
        float g = gate_p[0];
        for (int i = blockIdx.x * 256 + t; i < 8388608; i += 524288) {
            v4f v = x4[i];
            v4f r;
            r.x = fast_gelu(v.x) * g;
            r.y = fast_gelu(v.y) * g;
            r.z = fast_gelu(v.z) * g;
            r.w = fast_gelu(v.w) * g;
            o4[i] = r;
        }
    } else {
        int b2 = blockIdx.x - 2048;  // 0..31
        int ptr = ptrp[0];
        for (int k = 0; k < 16; ++k) {
            int i = b2 * 4096 + k * 256 + t;  // 131072 float4 total
            int row = i >> 8;
            v4f v = (row == ptr) ? mn4[i & 255] : buf4[i];
            ob4[i] = v;
        }
    }
}

extern "C" void kernel_launch(void* const* d_in, const int* in_sizes, int n_in,
                              void* d_out, int out_size, void* d_ws, size_t ws_size,
                              hipStream_t stream) {
    const float* x = (const float*)d_in[0];
    const float* log_k = (const float*)d_in[1];
    const float* log_lambda = (const float*)d_in[2];
    const float* buf = (const float*)d_in[3];
    const float* depl = (const float*)d_in[4];
    const int* hits = (const int*)d_in[5];
    const int* mask = (const int*)d_in[6];  // bool pushed as int32
    const int* ptr = (const int*)d_in[7];

    float* out = (float*)d_out;
    float* out_buf = out + 33554432;      // N*D
    float* out_depl = out_buf + NN * DD;  // 512
    float* out_hits = out_depl + NN;      // 512
    float* out_mask = out_hits + NN;      // 512

    // small scratch in ws (< 80 KB), exactly as R3
    float* wsf = (float*)d_ws;
    float* part2 = wsf;              // 16*1024
    float* m_mean = wsf + 16384;     // 1024
    float* m_n = wsf + 17408;        // 1024
    float* nm = wsf + 18432;         // 1
    float* gate = wsf + 18433;       // 1
    float* dot = wsf + 18440;        // 512
    float* sq = wsf + 18952;         // 512

    // big partial-sum scratch in the output region (4 MB), consumed before k_outbuf overwrites
    float* part = out;

    k_partial<<<dim3(PP), dim3(256), 0, stream>>>((const v4f*)x, (v4f*)part);
    k_reduce1<<<dim3(64), dim3(256), 0, stream>>>(part, part2);
    k_mean_norm<<<dim3(1), dim3(1024), 0, stream>>>(part2, m_mean, m_n, nm);
    k_sims<<<dim3(NN), dim3(256), 0, stream>>>((const v4f*)buf, (const v4f*)m_mean, dot, sq);
    k_state<<<dim3(1), dim3(512), 0, stream>>>(dot, sq, nm, depl, hits, mask,
                                               log_k, log_lambda, ptr,
                                               out_depl, out_hits, out_mask, gate);
    k_outbuf<<<dim3(2080), dim3(256), 0, stream>>>((const v4f*)x, (v4f*)out,
                                                   (const v4f*)buf, (const v4f*)m_n,
                                                   (v4f*)out_buf, gate, ptr);
}

// Round 9
// 100.863 us; speedup vs baseline: 1.3793x; 1.0100x over previous
//
#include <hip/hip_runtime.h>
#include <math.h>

#define BT 32768   // B*T tokens
#define DD 1024    // feature dim
#define NN 512     // buffer slots
#define PP 1024    // partial-sum blocks

typedef float v4f __attribute__((ext_vector_type(4)));

__device__ __forceinline__ float fast_gelu(float x) {
    // 0.5*x*(1+tanh(c*(x+0.044715 x^3))), tanh(u) = 1 - 2/(exp(2u)+1)
    float u = 0.7978845608028654f * (x + 0.044715f * x * x * x);
    float e = __expf(2.0f * u);
    float t = 1.0f - __fdividef(2.0f, e + 1.0f);
    return 0.5f * x * (1.0f + t);
}

// Pass 1a: per-column partial sums of gelu(x). part[PP][DD]  (R3/R7-proven, unchanged)
__global__ __launch_bounds__(256) void k_partial(const v4f* __restrict__ x4,
                                                 v4f* __restrict__ part) {
    int t = threadIdx.x;  // 0..255 -> cols 4t..4t+3
    v4f acc = {0.f, 0.f, 0.f, 0.f};
    for (int row = blockIdx.x; row < BT; row += PP) {
        v4f v = x4[row * (DD / 4) + t];
        acc.x += fast_gelu(v.x);
        acc.y += fast_gelu(v.y);
        acc.z += fast_gelu(v.z);
        acc.w += fast_gelu(v.w);
    }
    part[blockIdx.x * (DD / 4) + t] = acc;
}

// Pass 1b: reduce PP partial rows -> 16 rows. 64 blocks x 256 thr.  (unchanged)
__global__ __launch_bounds__(256) void k_reduce1(const float* __restrict__ part,
                                                 float* __restrict__ part2) {
    int g = blockIdx.x * 256 + threadIdx.x;  // 0..16383
    int col = g & (DD - 1);
    int chunk = g >> 10;  // 0..15
    float s = 0.f;
    int r0 = chunk * (PP / 16);
    for (int r = r0; r < r0 + PP / 16; ++r) s += part[r * DD + col];
    part2[chunk * DD + col] = s;
}

// sims: dot[n] = buf[n].m ; sq[n] = ||buf[n]||^2, with m computed on the fly
// from part2 (same summation order as the old k_mean_norm -> bit-identical dot).
__global__ __launch_bounds__(256) void k_sims(const v4f* __restrict__ buf4,
                                              const float* __restrict__ part2,
                                              float* __restrict__ dot,
                                              float* __restrict__ sq) {
    int n = blockIdx.x;
    int t = threadIdx.x;
    v4f b = buf4[n * (DD / 4) + t];
    float s0 = 0, s1 = 0, s2 = 0, s3 = 0;
    for (int r = 0; r < 16; ++r) {
        v4f p = ((const v4f*)(part2 + r * DD))[t];
        s0 += p.x; s1 += p.y; s2 += p.z; s3 += p.w;
    }
    const float inv = 1.0f / 32768.0f;
    float d = b.x * (s0 * inv) + b.y * (s1 * inv) + b.z * (s2 * inv) + b.w * (s3 * inv);
    float q = b.x * b.x + b.y * b.y + b.z * b.z + b.w * b.w;
    __shared__ float rd[256], rq[256];
    rd[t] = d;
    rq[t] = q;
    __syncthreads();
    for (int st = 128; st > 0; st >>= 1) {
        if (t < st) { rd[t] += rd[t + st]; rq[t] += rq[t + st]; }
        __syncthreads();
    }
    if (t == 0) { dot[n] = rd[0]; sq[n] = rq[0]; }
}

// state: computes nm from part2 itself (absorbs old k_mean_norm), then argmax
// (first-index tie-break), gate, small state outputs. Publishes nm for k_outbuf.
__global__ __launch_bounds__(512) void k_state(const float* __restrict__ part2,
                                               const float* __restrict__ dot,
                                               const float* __restrict__ sq,
                                               const float* __restrict__ depl,
                                               const int* __restrict__ hits,
                                               const int* __restrict__ mask,   // int32 on device
                                               const float* __restrict__ logk_p,
                                               const float* __restrict__ loglam_p,
                                               const int* __restrict__ ptr_p,
                                               float* __restrict__ out_depl,
                                               float* __restrict__ out_hits,
                                               float* __restrict__ out_mask,
                                               float* __restrict__ gate_p,
                                               float* __restrict__ nm_out) {
    int n = threadIdx.x;
    const float inv = 1.0f / 32768.0f;
    // ||m||: thread n handles cols n and n+512
    float sa = 0, sb = 0;
    for (int r = 0; r < 16; ++r) {
        sa += part2[r * DD + n];
        sb += part2[r * DD + n + 512];
    }
    float ma = sa * inv, mb = sb * inv;
    __shared__ float red[512];
    red[n] = ma * ma + mb * mb;
    __syncthreads();
    for (int st = 256; st > 0; st >>= 1) {
        if (n < st) red[n] += red[n + st];
        __syncthreads();
    }
    float nm = fmaxf(sqrtf(red[0]), 1e-12f);
    if (n == 0) nm_out[0] = sqrtf(red[0]);
    __syncthreads();

    float nb = fmaxf(sqrtf(sq[n]), 1e-12f);
    bool mk = mask[n] != 0;
    float sim = mk ? dot[n] / (nb * nm) : -1.0f;

    __shared__ float ssim[512];
    __shared__ int sidx[512];
    ssim[n] = sim;
    sidx[n] = n;
    __syncthreads();
    for (int st = 256; st > 0; st >>= 1) {
        if (n < st) {
            float s2 = ssim[n + st];
            int i2 = sidx[n + st];
            if (s2 > ssim[n] || (s2 == ssim[n] && i2 < sidx[n])) {
                ssim[n] = s2;
                sidx[n] = i2;
            }
        }
        __syncthreads();
    }

    __shared__ int s_near, s_fired;
    if (n == 0) {
        int nearest = sidx[0];
        float msim = ssim[0];
        float k_depl = fminf(fmaxf(expf(logk_p[0]), 0.1f), 5.0f);
        float lam = fminf(fmaxf(expf(loglam_p[0]), 0.1f), 3.0f);
        float g = expf(-k_depl * (1.0f - depl[nearest]) - lam * (float)hits[nearest]);
        s_near = nearest;
        s_fired = (msim > 0.85f) ? 1 : 0;
        gate_p[0] = g;
    }
    __syncthreads();

    int ptr = ptr_p[0];
    float nd = depl[n];
    int nh = hits[n];
    float nmsk = mk ? 1.0f : 0.0f;
    if (n == s_near && s_fired) { nd *= 0.5f; nh += 1; }
    if (n == ptr) { nd = 1.0f; nh = 0; nmsk = 1.0f; }
    out_depl[n] = nd;
    out_hits[n] = (float)nh;
    out_mask[n] = nmsk;
}

// Pass 2: blocks [0,2048): out = gelu(x)*gate (unchanged).
//         blocks [2048,2080): new_buf copy; ptr-row computes m_n from part2+nm.
__global__ __launch_bounds__(256) void k_outbuf(const v4f* __restrict__ x4,
                                                v4f* __restrict__ o4,
                                                const v4f* __restrict__ buf4,
                                                const float* __restrict__ part2,
                                                const float* __restrict__ nm_p,
                                                v4f* __restrict__ ob4,
                                                const float* __restrict__ gate_p,
                                                const int* __restrict__ ptrp) {
    int t = threadIdx.x;
    if (blockIdx.x < 2048) {
        float g = gate_p[0];
        for (int i = blockIdx.x * 256 + t; i < 8388608; i += 524288) {
            v4f v = x4[i];
            v4f r;
            r.x = fast_gelu(v.x) * g;
            r.y = fast_gelu(v.y) * g;
            r.z = fast_gelu(v.z) * g;
            r.w = fast_gelu(v.w) * g;
            o4[i] = r;
        }
    } else {
        int b2 = blockIdx.x - 2048;  // 0..31
        int ptr = ptrp[0];
        for (int k = 0; k < 16; ++k) {
            int i = b2 * 4096 + k * 256 + t;  // 131072 float4 total
            int row = i >> 8;  // 256 float4 per row
            v4f v;
            if (row == ptr) {
                int c4 = i & 255;
                float s0 = 0, s1 = 0, s2 = 0, s3 = 0;
                for (int r = 0; r < 16; ++r) {
                    v4f p = ((const v4f*)(part2 + r * DD))[c4];
                    s0 += p.x; s1 += p.y; s2 += p.z; s3 += p.w;
                }
                const float inv = 1.0f / 32768.0f;
                float den = fmaxf(nm_p[0], 1e-12f);
                v.x = s0 * inv / den;
                v.y = s1 * inv / den;
                v.z = s2 * inv / den;
                v.w = s3 * inv / den;
            } else {
                v = buf4[i];
            }
            ob4[i] = v;
        }
    }
}

extern "C" void kernel_launch(void* const* d_in, const int* in_sizes, int n_in,
                              void* d_out, int out_size, void* d_ws, size_t ws_size,
                              hipStream_t stream) {
    const float* x = (const float*)d_in[0];
    const float* log_k = (const float*)d_in[1];
    const float* log_lambda = (const float*)d_in[2];
    const float* buf = (const float*)d_in[3];
    const float* depl = (const float*)d_in[4];
    const int* hits = (const int*)d_in[5];
    const int* mask = (const int*)d_in[6];  // bool pushed as int32
    const int* ptr = (const int*)d_in[7];

    float* out = (float*)d_out;
    float* out_buf = out + 33554432;      // N*D
    float* out_depl = out_buf + NN * DD;  // 512
    float* out_hits = out_depl + NN;      // 512
    float* out_mask = out_hits + NN;      // 512

    // small scratch in ws
    float* wsf = (float*)d_ws;
    float* part2 = wsf;              // 16*1024 (64 KB)
    float* nm = wsf + 16384;         // 1
    float* gate = wsf + 16385;       // 1
    float* dot = wsf + 16400;        // 512
    float* sq = wsf + 16912;         // 512

    // big partial-sum scratch in the output region (4 MB), consumed before k_outbuf overwrites
    float* part = out;

    k_partial<<<dim3(PP), dim3(256), 0, stream>>>((const v4f*)x, (v4f*)part);
    k_reduce1<<<dim3(64), dim3(256), 0, stream>>>(part, part2);
    k_sims<<<dim3(NN), dim3(256), 0, stream>>>((const v4f*)buf, part2, dot, sq);
    k_state<<<dim3(1), dim3(512), 0, stream>>>(part2, dot, sq, depl, hits, mask,
                                               log_k, log_lambda, ptr,
                                               out_depl, out_hits, out_mask, gate, nm);
    k_outbuf<<<dim3(2080), dim3(256), 0, stream>>>((const v4f*)x, (v4f*)out,
                                                   (const v4f*)buf, part2, nm,
                                                   (v4f*)out_buf, gate, ptr);
}